// Round 9
// baseline (236.019 us; speedup 1.0000x reference)
//
#include <hip/hip_runtime.h>
#include <cstdint>

typedef __attribute__((ext_vector_type(8))) short short8;
typedef __attribute__((ext_vector_type(4))) float floatx4;

__device__ __forceinline__ unsigned short f2bf(float f) {
  uint32_t u = __builtin_bit_cast(uint32_t, f);
  u += 0x7fffu + ((u >> 16) & 1u);   // RNE
  return (unsigned short)(u >> 16);
}
// pack bf16(lo)|bf16(hi)<<16, round-half-up: 2 adds + 1 v_perm
__device__ __forceinline__ uint32_t pkbf(float lo, float hi) {
  uint32_t a = __builtin_bit_cast(uint32_t, lo) + 0x8000u;
  uint32_t b = __builtin_bit_cast(uint32_t, hi) + 0x8000u;
  return __builtin_amdgcn_perm(b, a, 0x07060302);
}
// async global->LDS, 16B per lane (HW: wave-uniform LDS base + lane*16)
__device__ __forceinline__ void gll16(const void* g, void* l) {
  __builtin_amdgcn_global_load_lds(
      (const __attribute__((address_space(1))) unsigned int*)g,
      (__attribute__((address_space(3))) unsigned int*)l, 16, 0, 0);
}

// ---------------- kernel 1: build Wt LDS-image (fp32 -> bf16, swizzled) --------
// [bz(3)][kb(24)][row(192)][cs(4)] 16B chunks; chunk cs holds data k-chunk
// c = cs ^ ((row>>1)&3)  (XOR bank swizzle baked into the image).
__global__ void prep_w_kernel(const float* __restrict__ Wq,
                              const float* __restrict__ Wk,
                              const float* __restrict__ Wv,
                              unsigned short* __restrict__ Wt) {
  int id = blockIdx.x * 256 + threadIdx.x;      // 55296 chunks total
  int bz = id / 18432, rem = id - bz * 18432;
  int kb = rem / 768, s = rem - kb * 768;
  int row = s >> 2, cs = s & 3;                  // row = output col nn 0..191
  int c = cs ^ ((row >> 1) & 3);
  const float* W = (bz == 0) ? Wq : (bz == 1) ? Wk : Wv;
  int k0 = kb * 32 + c * 8;
  unsigned short v[8];
#pragma unroll
  for (int e = 0; e < 8; ++e) v[e] = f2bf(W[(size_t)(k0 + e) * 192 + row]);
  uint4 o;
  o.x = v[0] | ((uint32_t)v[1] << 16);
  o.y = v[2] | ((uint32_t)v[3] << 16);
  o.z = v[4] | ((uint32_t)v[5] << 16);
  o.w = v[6] | ((uint32_t)v[7] << 16);
  *(uint4*)(Wt + (size_t)id * 8) = o;
}

// ---------------- kernel 2: QKV projection + RoPE (v8) ----------------
// v7 post-mortem: vmcnt(7) with 7 ops/body forced the PREVIOUS body's A-loads
// (HBM, ~1 iter old) to drain every iteration -- the prefetch slack was dead.
// v8, same geometry (128 rows x 192 cols, 24 MFMA/wave/iter, 3-buffer):
//  - exact ledger waits: steady vmcnt(11) = prevL(4)+thisD(3)+thisL(4) younger
//    than the target DMAB(KB); A-loads keep their full 2-iter slack (compiler
//    auto-waitcnt covers the pkbf uses).
//  - B-DMA issued 2 iters ahead, AFTER the barrier (write target last read
//    2 barriers earlier -> race-free); DMA slack ~300 -> ~800cy.
// Ledger (verified all 24 bodies): waits 19,23, 11 x19, tail 7/3/0.
__global__ __launch_bounds__(256, 2) void proj_kernel(
    const float* __restrict__ x, const unsigned short* __restrict__ Wt,
    unsigned short* __restrict__ q_ws, unsigned short* __restrict__ k_ws,
    unsigned short* __restrict__ v_ws) {
  __shared__ __align__(16) unsigned short A_lds[3][128 * 32];   // 3 x 8KB
  __shared__ __align__(16) unsigned short B_lds[3][192 * 32];   // 3 x 12KB
  const int tid = threadIdx.x;
  const int w = tid >> 6, l = tid & 63, quad = l >> 4, ln = l & 15;
  const int m0 = blockIdx.x * 128;
  const int bz = blockIdx.y;

  // A staging: thread owns chunks (row arow, ac) and (row arow+64, ac)
  const int arow = tid >> 2, ac = tid & 3;
  const int aslot = ((ac ^ ((arow >> 1) & 3)) << 4);  // same for arow+64
  const float* xp0 = x + (size_t)(m0 + arow) * 768 + ac * 8;
  const float* xp1 = xp0 + (size_t)64 * 768;
  const unsigned short* wimg = Wt + (size_t)bz * 18432 * 8;

  // fragment read chunk: (row>>1)&3 == (ln>>1)&3 (all frag row bases %8==0)
  const int fq = ((quad ^ ((ln >> 1) & 3)) << 4);

  floatx4 acc[2][12];
#pragma unroll
  for (int mi = 0; mi < 2; ++mi)
#pragma unroll
    for (int nj = 0; nj < 12; ++nj) acc[mi][nj] = floatx4{0.f, 0.f, 0.f, 0.f};

  // 3 rotating A-prefetch register sets, 2 rows each (4 float4)
  float4 a0p, a0q, a0r, a0s, a1p, a1q, a1r, a1s, a2p, a2q, a2r, a2s;

#define LOADA(S, K0)                               \
  do {                                             \
    a##S##p = *(const float4*)(xp0 + (K0));        \
    a##S##q = *(const float4*)(xp0 + (K0) + 4);    \
    a##S##r = *(const float4*)(xp1 + (K0));        \
    a##S##s = *(const float4*)(xp1 + (K0) + 4);    \
  } while (0)
#define STAGEA(S, AB)                                                   \
  do {                                                                  \
    uint4 ap;                                                           \
    ap.x = pkbf(a##S##p.x, a##S##p.y);                                  \
    ap.y = pkbf(a##S##p.z, a##S##p.w);                                  \
    ap.z = pkbf(a##S##q.x, a##S##q.y);                                  \
    ap.w = pkbf(a##S##q.z, a##S##q.w);                                  \
    *(uint4*)((char*)&A_lds[AB][0] + arow * 64 + aslot) = ap;           \
    ap.x = pkbf(a##S##r.x, a##S##r.y);                                  \
    ap.y = pkbf(a##S##r.z, a##S##r.w);                                  \
    ap.z = pkbf(a##S##s.x, a##S##s.y);                                  \
    ap.w = pkbf(a##S##s.z, a##S##s.w);                                  \
    *(uint4*)((char*)&A_lds[AB][0] + (arow + 64) * 64 + aslot) = ap;    \
  } while (0)
#define DMAB(KB1, BB)                                             \
  do {                                                            \
    const unsigned short* src = wimg + (size_t)(KB1)*6144;        \
    char* dstb = (char*)&B_lds[BB][0];                            \
    gll16(src + tid * 8, dstb + tid * 16);                        \
    gll16(src + (256 + tid) * 8, dstb + (256 + tid) * 16);        \
    gll16(src + (512 + tid) * 8, dstb + (512 + tid) * 16);        \
  } while (0)
#define WAITBAR(N)                                                          \
  asm volatile("s_waitcnt vmcnt(" #N ") lgkmcnt(0)\n\ts_barrier" ::: "memory")
#define PCOMPUTE(C)                                                              \
  do {                                                                           \
    short8 af0 = *(const short8*)((const char*)&A_lds[C][0] +                    \
                                  (w * 32 + ln) * 64 + fq);                      \
    short8 af1 = *(const short8*)((const char*)&A_lds[C][0] +                    \
                                  (w * 32 + 16 + ln) * 64 + fq);                 \
    _Pragma("unroll") for (int nj = 0; nj < 12; ++nj) {                          \
      short8 bf = *(const short8*)((const char*)&B_lds[C][0] +                   \
                                   (nj * 16 + ln) * 64 + fq);                    \
      acc[0][nj] = __builtin_amdgcn_mfma_f32_16x16x32_bf16(af0, bf, acc[0][nj],  \
                                                           0, 0, 0);             \
      acc[1][nj] = __builtin_amdgcn_mfma_f32_16x16x32_bf16(af1, bf, acc[1][nj],  \
                                                           0, 0, 0);             \
    }                                                                            \
  } while (0)
// Steady body KB (C=KB%3, P=(KB+1)%3, N2=(KB+2)%3):
//   STAGEA(P->bufP)  (set P loaded 2 bodies ago; compiler waits its loads)
//   LOADA(C, KB+3)   (reload set C, consumed 2 bodies later)
//   WAITBAR(11)      (drains DMAB(KB), issued 2 bodies ago post-barrier)
//   DMAB(KB+2 ->N2)  (post-barrier: target last read 2 barriers ago)
//   PCOMPUTE(C)
#define BODY(KB, C, P, N2)        \
  do {                            \
    STAGEA(P, P);                 \
    LOADA(C, ((KB) + 3) * 32);    \
    WAITBAR(11);                  \
    DMAB((KB) + 2, N2);           \
    PCOMPUTE(C);                  \
  } while (0)

  // prologue: D0,D1; A-load sets k0,k1,k2; stage set0->buf0
  DMAB(0, 0);
  DMAB(1, 1);
  LOADA(0, 0);
  LOADA(1, 32);
  LOADA(2, 64);
  STAGEA(0, 0);

  // body 0: target D0; younger = D1(3)+prologue L(12)+this L(4) = 19
  { STAGEA(1, 1); LOADA(0, 96); WAITBAR(19); DMAB(2, 2); PCOMPUTE(0); }
  // body 1: target D1; younger = prologue L(12)+B0 L(4)+D2(3)+this L(4) = 23
  { STAGEA(2, 2); LOADA(1, 128); WAITBAR(23); DMAB(3, 0); PCOMPUTE(1); }
  // bodies 2..19
  for (int t = 2; t <= 17; t += 3) {
    BODY(t, 2, 0, 1);
    BODY(t + 1, 0, 1, 2);
    BODY(t + 2, 1, 2, 0);
  }
  BODY(20, 2, 0, 1);
  // body 21: no LOADA; target D21; younger = B20 L(4)+D22(3) = 7
  { STAGEA(1, 1); WAITBAR(7); DMAB(23, 2); PCOMPUTE(0); }
  // body 22: no LOADA, no DMA; target D22; younger = D23(3) = 3
  { STAGEA(2, 2); WAITBAR(3); PCOMPUTE(1); }
  // body 23: drain
  { WAITBAR(0); PCOMPUTE(2); }
#undef LOADA
#undef STAGEA
#undef DMAB
#undef WAITBAR
#undef PCOMPUTE
#undef BODY

  // epilogue. wave w: rows m0 + w*32 + mi*16 + quad*4 + r; cols nj*16+ln.
  // bz 0: Q (RoPE nj0,1) | bz 1: K (RoPE nj0,1) | bz 2: V transposed [b][dim][t]
  const float R_LG = 0.8304820237218406f;  // log2(10000)/16
  if (bz < 2) {
    unsigned short* dst = (bz == 0) ? q_ws : k_ws;
#pragma unroll
    for (int mi = 0; mi < 2; ++mi)
#pragma unroll
      for (int r = 0; r < 4; ++r) {
        int row_g = m0 + w * 32 + mi * 16 + quad * 4 + r;
        int t_pos = row_g & 511;
        float v0 = acc[mi][0][r], v1 = acc[mi][1][r];
        {
          float i0 = (float)(ln >> 1);
          float f0 = exp2f(-i0 * R_LG);
          float f1 = exp2f(-(i0 + 8.0f) * R_LG);
          float s0, c0, s1, c1;
          sincosf((float)t_pos * f0, &s0, &c0);
          sincosf((float)t_pos * f1, &s1, &c1);
          float p0 = __shfl_xor(v0, 1), p1 = __shfl_xor(v1, 1);
          v0 = (ln & 1) ? (v0 * c0 + p0 * s0) : (v0 * c0 - p0 * s0);
          v1 = (ln & 1) ? (v1 * c1 + p1 * s1) : (v1 * c1 - p1 * s1);
        }
        dst[(size_t)row_g * 192 + ln] = f2bf(v0);
        dst[(size_t)row_g * 192 + 16 + ln] = f2bf(v1);
#pragma unroll
        for (int nj = 2; nj < 12; ++nj)
          dst[(size_t)row_g * 192 + nj * 16 + ln] = f2bf(acc[mi][nj][r]);
      }
  } else {
#pragma unroll
    for (int mi = 0; mi < 2; ++mi) {
      int rb = m0 + w * 32 + mi * 16 + quad * 4;  // 4 consecutive rows, one batch
      int bb = rb >> 9, t = rb & 511;
#pragma unroll
      for (int nj = 0; nj < 12; ++nj) {
        ushort4 pv;
        pv.x = f2bf(acc[mi][nj][0]);
        pv.y = f2bf(acc[mi][nj][1]);
        pv.z = f2bf(acc[mi][nj][2]);
        pv.w = f2bf(acc[mi][nj][3]);
        *(ushort4*)&v_ws[((size_t)bb * 192 + nj * 16 + ln) * 512 + t] = pv;
      }
    }
  }
}

// ---------------- kernel 3: causal flash attention (MFMA, KVBLK=32) -----------
// UNCHANGED from the passing round-7/8 version (2 blocks/CU).
__global__ __launch_bounds__(256) void attn_kernel(
    const unsigned short* __restrict__ q_ws, const unsigned short* __restrict__ k_ws,
    const unsigned short* __restrict__ v_ws, float* __restrict__ out) {
  __shared__ __align__(16) unsigned short K_lds[32 * 200];
  __shared__ __align__(16) unsigned short V_lds[192 * 40];   // V^T: [dim][key]
  __shared__ __align__(16) unsigned short P_lds[4][16 * 40]; // per-wave P
  const int tid = threadIdx.x;
  const int w = tid >> 6, l = tid & 63, quad = l >> 4, ln = l & 15;
  const int b = blockIdx.y;
  const int qt = (blockIdx.y < 32) ? blockIdx.x : 7 - blockIdx.x;
  const int q0 = qt * 64;

  // preload Q A-fragments
  short8 qf[6];
  {
    const unsigned short* qp =
        q_ws + (size_t)(b * 512 + q0 + w * 16 + ln) * 192 + quad * 8;
#pragma unroll
    for (int kk = 0; kk < 6; ++kk) qf[kk] = *(const short8*)(qp + kk * 32);
  }

  float m_i[4], l_i[4];
  floatx4 o[12];
#pragma unroll
  for (int r = 0; r < 4; ++r) { m_i[r] = -1e30f; l_i[r] = 0.f; }
#pragma unroll
  for (int nt = 0; nt < 12; ++nt) o[nt] = floatx4{0.f, 0.f, 0.f, 0.f};
  const float sm_scale = 0.07216878364870323f;  // 192^-0.5

  const int ktmax = 2 * qt + 1;
  for (int kt = 0; kt <= ktmax; ++kt) {
    const int k0 = kt * 32;
    __syncthreads();  // previous iteration's LDS reads done before overwrite
    // stage K tile [32][192]: 768 16B chunks
#pragma unroll
    for (int it = 0; it < 3; ++it) {
      int idx = it * 256 + tid;
      int row = idx / 24, c = idx - row * 24;
      uint4 v = *(const uint4*)(k_ws + (size_t)(b * 512 + k0 + row) * 192 + c * 8);
      *(uint4*)&K_lds[row * 200 + c * 8] = v;
    }
    // stage V^T tile [192][32]: 768 chunks
#pragma unroll
    for (int it = 0; it < 3; ++it) {
      int idx = it * 256 + tid;
      int row = idx >> 2, c = idx & 3;
      uint4 v = *(const uint4*)(v_ws + (size_t)(b * 192 + row) * 512 + k0 + c * 8);
      *(uint4*)&V_lds[row * 40 + c * 8] = v;
    }
    __syncthreads();

    // S = Q K^T (scaled)
    float s[2][4];
    __builtin_amdgcn_s_setprio(1);
#pragma unroll
    for (int nt = 0; nt < 2; ++nt) {
      floatx4 sa = floatx4{0.f, 0.f, 0.f, 0.f};
#pragma unroll
      for (int kk = 0; kk < 6; ++kk) {
        short8 kf = *(const short8*)&K_lds[(nt * 16 + ln) * 200 + kk * 32 + quad * 8];
        sa = __builtin_amdgcn_mfma_f32_16x16x32_bf16(qf[kk], kf, sa, 0, 0, 0);
      }
#pragma unroll
      for (int r = 0; r < 4; ++r) s[nt][r] = sa[r] * sm_scale;
    }
    __builtin_amdgcn_s_setprio(0);
    if (kt >= 2 * qt) {  // diagonal-region tiles
      int kd = (kt - 2 * qt) * 32;
#pragma unroll
      for (int nt = 0; nt < 2; ++nt)
#pragma unroll
        for (int r = 0; r < 4; ++r)
          if (kd + nt * 16 + ln > w * 16 + quad * 4 + r) s[nt][r] = -1e30f;
    }
    // online softmax (row = quad*4+r)
    float alpha[4];
#pragma unroll
    for (int r = 0; r < 4; ++r) {
      float mx = fmaxf(s[0][r], s[1][r]);
      mx = fmaxf(mx, __shfl_xor(mx, 1));
      mx = fmaxf(mx, __shfl_xor(mx, 2));
      mx = fmaxf(mx, __shfl_xor(mx, 4));
      mx = fmaxf(mx, __shfl_xor(mx, 8));
      float mnew = fmaxf(m_i[r], mx);
      alpha[r] = __expf(m_i[r] - mnew);
      float sum = 0.f;
#pragma unroll
      for (int nt = 0; nt < 2; ++nt) {
        s[nt][r] = __expf(s[nt][r] - mnew);
        sum += s[nt][r];
      }
      sum += __shfl_xor(sum, 1);
      sum += __shfl_xor(sum, 2);
      sum += __shfl_xor(sum, 4);
      sum += __shfl_xor(sum, 8);
      l_i[r] = l_i[r] * alpha[r] + sum;
      m_i[r] = mnew;
    }
#pragma unroll
    for (int nt = 0; nt < 12; ++nt)
#pragma unroll
      for (int r = 0; r < 4; ++r) o[nt][r] *= alpha[r];

    // P: C/D layout -> A layout via per-wave LDS
#pragma unroll
    for (int nt = 0; nt < 2; ++nt)
#pragma unroll
      for (int r = 0; r < 4; ++r)
        P_lds[w][(quad * 4 + r) * 40 + nt * 16 + ln] = f2bf(s[nt][r]);
    __asm__ volatile("s_waitcnt lgkmcnt(0)" ::: "memory");  // wave-local write->read

    // O += P V (single k-slab: KVBLK=32)
    __builtin_amdgcn_s_setprio(1);
    {
      short8 pf = *(const short8*)&P_lds[w][ln * 40 + quad * 8];
#pragma unroll
      for (int nt = 0; nt < 12; ++nt) {
        short8 vf = *(const short8*)&V_lds[(nt * 16 + ln) * 40 + quad * 8];
        o[nt] = __builtin_amdgcn_mfma_f32_16x16x32_bf16(pf, vf, o[nt], 0, 0, 0);
      }
    }
    __builtin_amdgcn_s_setprio(0);
  }

  // epilogue: O/l -> fp32 out [b][t][dim]
#pragma unroll
  for (int r = 0; r < 4; ++r) {
    float inv = 1.0f / l_i[r];
    size_t rowoff = (size_t)(b * 512 + q0 + w * 16 + quad * 4 + r) * 192;
#pragma unroll
    for (int nt = 0; nt < 12; ++nt)
      out[rowoff + nt * 16 + ln] = o[nt][r] * inv;
  }
}

extern "C" void kernel_launch(void* const* d_in, const int* in_sizes, int n_in,
                              void* d_out, int out_size, void* d_ws, size_t ws_size,
                              hipStream_t stream) {
  const float* x = (const float*)d_in[0];
  const float* Wq = (const float*)d_in[1];
  const float* Wk = (const float*)d_in[2];
  const float* Wv = (const float*)d_in[3];
  float* out = (float*)d_out;

  char* ws = (char*)d_ws;
  const size_t QKV_BYTES = (size_t)64 * 512 * 192 * 2;  // 12,582,912
  unsigned short* q_ws = (unsigned short*)(ws);
  unsigned short* k_ws = (unsigned short*)(ws + QKV_BYTES);
  unsigned short* v_ws = (unsigned short*)(ws + 2 * QKV_BYTES);
  unsigned short* Wt = (unsigned short*)(ws + 3 * QKV_BYTES);  // 884,736 B image

  hipLaunchKernelGGL(prep_w_kernel, dim3(216), dim3(256), 0, stream, Wq, Wk, Wv, Wt);
  hipLaunchKernelGGL(proj_kernel, dim3(256, 3), dim3(256), 0, stream, x, Wt, q_ws, k_ws, v_ws);
  hipLaunchKernelGGL(attn_kernel, dim3(8, 64), dim3(256), 0, stream, q_ws, k_ws, v_ws, out);
}

// Round 10
// 235.672 us; speedup vs baseline: 1.0015x; 1.0015x over previous
//
#include <hip/hip_runtime.h>
#include <cstdint>

typedef __attribute__((ext_vector_type(8))) short short8;
typedef __attribute__((ext_vector_type(4))) float floatx4;

__device__ __forceinline__ unsigned short f2bf(float f) {
  uint32_t u = __builtin_bit_cast(uint32_t, f);
  u += 0x7fffu + ((u >> 16) & 1u);   // RNE
  return (unsigned short)(u >> 16);
}
// pack bf16(lo)|bf16(hi)<<16, round-half-up: 2 adds + 1 v_perm
__device__ __forceinline__ uint32_t pkbf(float lo, float hi) {
  uint32_t a = __builtin_bit_cast(uint32_t, lo) + 0x8000u;
  uint32_t b = __builtin_bit_cast(uint32_t, hi) + 0x8000u;
  return __builtin_amdgcn_perm(b, a, 0x07060302);
}
// async global->LDS, 16B per lane (HW: wave-uniform LDS base + lane*16;
// the GLOBAL source address is per-lane -> swizzles live in the source)
__device__ __forceinline__ void gll16(const void* g, void* l) {
  __builtin_amdgcn_global_load_lds(
      (const __attribute__((address_space(1))) unsigned int*)g,
      (__attribute__((address_space(3))) unsigned int*)l, 16, 0, 0);
}

// ---------------- kernel 1: build Wt LDS-image (fp32 -> bf16, swizzled) --------
// [bz(3)][kb(24)][row(192)][cs(4)] 16B chunks; chunk cs holds data k-chunk
// c = cs ^ ((row>>1)&3)  (XOR bank swizzle baked into the image).
__global__ void prep_w_kernel(const float* __restrict__ Wq,
                              const float* __restrict__ Wk,
                              const float* __restrict__ Wv,
                              unsigned short* __restrict__ Wt) {
  int id = blockIdx.x * 256 + threadIdx.x;      // 55296 chunks total
  int bz = id / 18432, rem = id - bz * 18432;
  int kb = rem / 768, s = rem - kb * 768;
  int row = s >> 2, cs = s & 3;                  // row = output col nn 0..191
  int c = cs ^ ((row >> 1) & 3);
  const float* W = (bz == 0) ? Wq : (bz == 1) ? Wk : Wv;
  int k0 = kb * 32 + c * 8;
  unsigned short v[8];
#pragma unroll
  for (int e = 0; e < 8; ++e) v[e] = f2bf(W[(size_t)(k0 + e) * 192 + row]);
  uint4 o;
  o.x = v[0] | ((uint32_t)v[1] << 16);
  o.y = v[2] | ((uint32_t)v[3] << 16);
  o.z = v[4] | ((uint32_t)v[5] << 16);
  o.w = v[6] | ((uint32_t)v[7] << 16);
  *(uint4*)(Wt + (size_t)id * 8) = o;
}

// ---------------- kernel 2: QKV projection + RoPE (v9: pure-DMA both operands) -
// Five sync variants all flat at 78-90us -> the A register-staging chain
// (global->VGPR->pkbf->ds_write) is the drag, not wait discipline. v9 DMAs A
// DIRECTLY from fp32 x into LDS (no prep pass, no staging VALU); fp32->bf16
// happens at fragment-read (2x ds_read_b128 + 4 pkbf per fragment).
// A_lds fp32 [3][128rows][8 slots x 16B], slot s of row holds data chunk
// s^(row&7) (inverse perm in the per-lane GLOBAL src; LDS write lane-linear).
// Read slots (2q)^(ln&7), ^1 -> 8 distinct banks-groups, 2-way max (free).
// B: bf16 pre-swizzled image, 2-buf. Body: WAITBAR(4) -> DMAB(i+1) ->
// DMAA(i+2) -> compute(i); post-barrier issue makes 2/3-buf reuse race-free;
// vmcnt(4) = exactly "A(i),B(i) drained; A(i+1) (HBM, 2-iter slack) in flight".
// LDS 72KB -> 2 blocks/CU.
__global__ __launch_bounds__(256, 2) void proj_kernel(
    const float* __restrict__ x, const unsigned short* __restrict__ Wt,
    unsigned short* __restrict__ q_ws, unsigned short* __restrict__ k_ws,
    unsigned short* __restrict__ v_ws) {
  __shared__ __align__(16) float A_lds[3][128 * 32];            // 3 x 16KB fp32
  __shared__ __align__(16) unsigned short B_lds[2][192 * 32];   // 2 x 12KB bf16
  const int tid = threadIdx.x;
  const int w = tid >> 6, l = tid & 63, quad = l >> 4, ln = l & 15;
  const int m0 = blockIdx.x * 128;
  const int bz = blockIdx.y;

  // A DMA source: thread t, iteration it -> row it*32 + (t>>3), slot t&7.
  // Slot cs receives data chunk cs^(row&7): inverse-perm the source column.
  const int arow7 = (tid >> 3) & 7;                 // row&7 (it*32 preserves it)
  const int aswz = (tid & 7) ^ arow7;               // data chunk for this slot
  const float* xsrc = x + (size_t)(m0 + (tid >> 3)) * 768 + aswz * 4;
  const unsigned short* wimg = Wt + (size_t)bz * 18432 * 8;

  // B fragment read chunk (bf16 rows, 4 chunks): (row>>1)&3 == (ln>>1)&3
  const int fq = ((quad ^ ((ln >> 1) & 3)) << 4);
  // A fragment read slots (fp32 rows, 8 chunks): row&7 == ln&7
  const int as0 = ((2 * quad) ^ (ln & 7)) << 4;     // byte offset of data chunk 2q
  const int as1 = as0 ^ 16;                          // data chunk 2q+1

  floatx4 acc[2][12];
#pragma unroll
  for (int mi = 0; mi < 2; ++mi)
#pragma unroll
    for (int nj = 0; nj < 12; ++nj) acc[mi][nj] = floatx4{0.f, 0.f, 0.f, 0.f};

#define DMAA(KB, AB)                                                    \
  do {                                                                  \
    char* dsta = (char*)&A_lds[AB][0];                                  \
    _Pragma("unroll") for (int it = 0; it < 4; ++it)                    \
        gll16(xsrc + (size_t)it * 32 * 768 + (KB) * 32,                 \
              dsta + (it * 256 + tid) * 16);                            \
  } while (0)
#define DMAB(KB, BB)                                              \
  do {                                                            \
    const unsigned short* src = wimg + (size_t)(KB)*6144;         \
    char* dstb = (char*)&B_lds[BB][0];                            \
    gll16(src + tid * 8, dstb + tid * 16);                        \
    gll16(src + (256 + tid) * 8, dstb + (256 + tid) * 16);        \
    gll16(src + (512 + tid) * 8, dstb + (512 + tid) * 16);        \
  } while (0)
#define WAITBAR(N)                                                          \
  asm volatile("s_waitcnt vmcnt(" #N ") lgkmcnt(0)\n\ts_barrier" ::: "memory")
// A-fragment: 2 ds_read_b128 (fp32) + 4 pkbf -> short8
#define AFRAG(DST, CA, ROWB)                                                  \
  short8 DST;                                                                 \
  do {                                                                        \
    const char* ab = (const char*)&A_lds[CA][0] + (ROWB) * 128;               \
    float4 c0 = *(const float4*)(ab + as0);                                   \
    float4 c1 = *(const float4*)(ab + as1);                                   \
    uint4 u = {pkbf(c0.x, c0.y), pkbf(c0.z, c0.w),                            \
               pkbf(c1.x, c1.y), pkbf(c1.z, c1.w)};                           \
    DST = __builtin_bit_cast(short8, u);                                      \
  } while (0)
#define PCOMPUTE(CA, CB)                                                         \
  do {                                                                           \
    AFRAG(af0, CA, w * 32 + ln);                                                 \
    AFRAG(af1, CA, w * 32 + 16 + ln);                                            \
    _Pragma("unroll") for (int nj = 0; nj < 12; ++nj) {                          \
      short8 bf = *(const short8*)((const char*)&B_lds[CB][0] +                  \
                                   (nj * 16 + ln) * 64 + fq);                    \
      acc[0][nj] = __builtin_amdgcn_mfma_f32_16x16x32_bf16(af0, bf, acc[0][nj],  \
                                                           0, 0, 0);             \
      acc[1][nj] = __builtin_amdgcn_mfma_f32_16x16x32_bf16(af1, bf, acc[1][nj],  \
                                                           0, 0, 0);             \
    }                                                                            \
  } while (0)
// Body J (steady): drain A(J),B(J) (younger = A(J+1):4 -> vmcnt(4));
// post-barrier issue B(J+1) (1-ahead, L2) and A(J+2) (2-ahead, HBM).
#define BODY(J, AN, BN, CA, CB)   \
  do {                            \
    WAITBAR(4);                   \
    DMAB((J) + 1, BN);            \
    DMAA((J) + 2, AN);            \
    PCOMPUTE(CA, CB);             \
  } while (0)

  // prologue: B(0)->b0 [3], A(0)->a0 [4], A(1)->a1 [4]  (11 outstanding)
  DMAB(0, 0);
  DMAA(0, 0);
  DMAA(1, 1);

  // bodies 0..21 (period-6 buffer pattern), tails 22, 23
  for (int t = 0; t < 18; t += 6) {
    BODY(t + 0, 2, 1, 0, 0);
    BODY(t + 1, 0, 0, 1, 1);
    BODY(t + 2, 1, 1, 2, 0);
    BODY(t + 3, 2, 0, 0, 1);
    BODY(t + 4, 0, 1, 1, 0);
    BODY(t + 5, 1, 0, 2, 1);
  }
  BODY(18, 2, 1, 0, 0);
  BODY(19, 0, 0, 1, 1);
  BODY(20, 1, 1, 2, 0);
  BODY(21, 2, 0, 0, 1);
  { WAITBAR(4); DMAB(23, 1); PCOMPUTE(1, 0); }  // body 22 (no A issue)
  { WAITBAR(0); PCOMPUTE(2, 1); }               // body 23 drain
#undef DMAA
#undef DMAB
#undef WAITBAR
#undef AFRAG
#undef PCOMPUTE
#undef BODY

  // epilogue. wave w: rows m0 + w*32 + mi*16 + quad*4 + r; cols nj*16+ln.
  // bz 0: Q (RoPE nj0,1) | bz 1: K (RoPE nj0,1) | bz 2: V transposed [b][dim][t]
  const float R_LG = 0.8304820237218406f;  // log2(10000)/16
  if (bz < 2) {
    unsigned short* dst = (bz == 0) ? q_ws : k_ws;
#pragma unroll
    for (int mi = 0; mi < 2; ++mi)
#pragma unroll
      for (int r = 0; r < 4; ++r) {
        int row_g = m0 + w * 32 + mi * 16 + quad * 4 + r;
        int t_pos = row_g & 511;
        float v0 = acc[mi][0][r], v1 = acc[mi][1][r];
        {
          float i0 = (float)(ln >> 1);
          float f0 = exp2f(-i0 * R_LG);
          float f1 = exp2f(-(i0 + 8.0f) * R_LG);
          float s0, c0, s1, c1;
          sincosf((float)t_pos * f0, &s0, &c0);
          sincosf((float)t_pos * f1, &s1, &c1);
          float p0 = __shfl_xor(v0, 1), p1 = __shfl_xor(v1, 1);
          v0 = (ln & 1) ? (v0 * c0 + p0 * s0) : (v0 * c0 - p0 * s0);
          v1 = (ln & 1) ? (v1 * c1 + p1 * s1) : (v1 * c1 - p1 * s1);
        }
        dst[(size_t)row_g * 192 + ln] = f2bf(v0);
        dst[(size_t)row_g * 192 + 16 + ln] = f2bf(v1);
#pragma unroll
        for (int nj = 2; nj < 12; ++nj)
          dst[(size_t)row_g * 192 + nj * 16 + ln] = f2bf(acc[mi][nj][r]);
      }
  } else {
#pragma unroll
    for (int mi = 0; mi < 2; ++mi) {
      int rb = m0 + w * 32 + mi * 16 + quad * 4;  // 4 consecutive rows, one batch
      int bb = rb >> 9, t = rb & 511;
#pragma unroll
      for (int nj = 0; nj < 12; ++nj) {
        ushort4 pv;
        pv.x = f2bf(acc[mi][nj][0]);
        pv.y = f2bf(acc[mi][nj][1]);
        pv.z = f2bf(acc[mi][nj][2]);
        pv.w = f2bf(acc[mi][nj][3]);
        *(ushort4*)&v_ws[((size_t)bb * 192 + nj * 16 + ln) * 512 + t] = pv;
      }
    }
  }
}

// ---------------- kernel 3: causal flash attention (MFMA, KVBLK=32) -----------
// UNCHANGED from the passing round-8/9 version (2 blocks/CU).
__global__ __launch_bounds__(256) void attn_kernel(
    const unsigned short* __restrict__ q_ws, const unsigned short* __restrict__ k_ws,
    const unsigned short* __restrict__ v_ws, float* __restrict__ out) {
  __shared__ __align__(16) unsigned short K_lds[32 * 200];
  __shared__ __align__(16) unsigned short V_lds[192 * 40];   // V^T: [dim][key]
  __shared__ __align__(16) unsigned short P_lds[4][16 * 40]; // per-wave P
  const int tid = threadIdx.x;
  const int w = tid >> 6, l = tid & 63, quad = l >> 4, ln = l & 15;
  const int b = blockIdx.y;
  const int qt = (blockIdx.y < 32) ? blockIdx.x : 7 - blockIdx.x;
  const int q0 = qt * 64;

  // preload Q A-fragments
  short8 qf[6];
  {
    const unsigned short* qp =
        q_ws + (size_t)(b * 512 + q0 + w * 16 + ln) * 192 + quad * 8;
#pragma unroll
    for (int kk = 0; kk < 6; ++kk) qf[kk] = *(const short8*)(qp + kk * 32);
  }

  float m_i[4], l_i[4];
  floatx4 o[12];
#pragma unroll
  for (int r = 0; r < 4; ++r) { m_i[r] = -1e30f; l_i[r] = 0.f; }
#pragma unroll
  for (int nt = 0; nt < 12; ++nt) o[nt] = floatx4{0.f, 0.f, 0.f, 0.f};
  const float sm_scale = 0.07216878364870323f;  // 192^-0.5

  const int ktmax = 2 * qt + 1;
  for (int kt = 0; kt <= ktmax; ++kt) {
    const int k0 = kt * 32;
    __syncthreads();  // previous iteration's LDS reads done before overwrite
    // stage K tile [32][192]: 768 16B chunks
#pragma unroll
    for (int it = 0; it < 3; ++it) {
      int idx = it * 256 + tid;
      int row = idx / 24, c = idx - row * 24;
      uint4 v = *(const uint4*)(k_ws + (size_t)(b * 512 + k0 + row) * 192 + c * 8);
      *(uint4*)&K_lds[row * 200 + c * 8] = v;
    }
    // stage V^T tile [192][32]: 768 chunks
#pragma unroll
    for (int it = 0; it < 3; ++it) {
      int idx = it * 256 + tid;
      int row = idx >> 2, c = idx & 3;
      uint4 v = *(const uint4*)(v_ws + (size_t)(b * 192 + row) * 512 + k0 + c * 8);
      *(uint4*)&V_lds[row * 40 + c * 8] = v;
    }
    __syncthreads();

    // S = Q K^T (scaled)
    float s[2][4];
    __builtin_amdgcn_s_setprio(1);
#pragma unroll
    for (int nt = 0; nt < 2; ++nt) {
      floatx4 sa = floatx4{0.f, 0.f, 0.f, 0.f};
#pragma unroll
      for (int kk = 0; kk < 6; ++kk) {
        short8 kf = *(const short8*)&K_lds[(nt * 16 + ln) * 200 + kk * 32 + quad * 8];
        sa = __builtin_amdgcn_mfma_f32_16x16x32_bf16(qf[kk], kf, sa, 0, 0, 0);
      }
#pragma unroll
      for (int r = 0; r < 4; ++r) s[nt][r] = sa[r] * sm_scale;
    }
    __builtin_amdgcn_s_setprio(0);
    if (kt >= 2 * qt) {  // diagonal-region tiles
      int kd = (kt - 2 * qt) * 32;
#pragma unroll
      for (int nt = 0; nt < 2; ++nt)
#pragma unroll
        for (int r = 0; r < 4; ++r)
          if (kd + nt * 16 + ln > w * 16 + quad * 4 + r) s[nt][r] = -1e30f;
    }
    // online softmax (row = quad*4+r)
    float alpha[4];
#pragma unroll
    for (int r = 0; r < 4; ++r) {
      float mx = fmaxf(s[0][r], s[1][r]);
      mx = fmaxf(mx, __shfl_xor(mx, 1));
      mx = fmaxf(mx, __shfl_xor(mx, 2));
      mx = fmaxf(mx, __shfl_xor(mx, 4));
      mx = fmaxf(mx, __shfl_xor(mx, 8));
      float mnew = fmaxf(m_i[r], mx);
      alpha[r] = __expf(m_i[r] - mnew);
      float sum = 0.f;
#pragma unroll
      for (int nt = 0; nt < 2; ++nt) {
        s[nt][r] = __expf(s[nt][r] - mnew);
        sum += s[nt][r];
      }
      sum += __shfl_xor(sum, 1);
      sum += __shfl_xor(sum, 2);
      sum += __shfl_xor(sum, 4);
      sum += __shfl_xor(sum, 8);
      l_i[r] = l_i[r] * alpha[r] + sum;
      m_i[r] = mnew;
    }
#pragma unroll
    for (int nt = 0; nt < 12; ++nt)
#pragma unroll
      for (int r = 0; r < 4; ++r) o[nt][r] *= alpha[r];

    // P: C/D layout -> A layout via per-wave LDS
#pragma unroll
    for (int nt = 0; nt < 2; ++nt)
#pragma unroll
      for (int r = 0; r < 4; ++r)
        P_lds[w][(quad * 4 + r) * 40 + nt * 16 + ln] = f2bf(s[nt][r]);
    __asm__ volatile("s_waitcnt lgkmcnt(0)" ::: "memory");  // wave-local write->read

    // O += P V (single k-slab: KVBLK=32)
    __builtin_amdgcn_s_setprio(1);
    {
      short8 pf = *(const short8*)&P_lds[w][ln * 40 + quad * 8];
#pragma unroll
      for (int nt = 0; nt < 12; ++nt) {
        short8 vf = *(const short8*)&V_lds[(nt * 16 + ln) * 40 + quad * 8];
        o[nt] = __builtin_amdgcn_mfma_f32_16x16x32_bf16(pf, vf, o[nt], 0, 0, 0);
      }
    }
    __builtin_amdgcn_s_setprio(0);
  }

  // epilogue: O/l -> fp32 out [b][t][dim]
#pragma unroll
  for (int r = 0; r < 4; ++r) {
    float inv = 1.0f / l_i[r];
    size_t rowoff = (size_t)(b * 512 + q0 + w * 16 + quad * 4 + r) * 192;
#pragma unroll
    for (int nt = 0; nt < 12; ++nt)
      out[rowoff + nt * 16 + ln] = o[nt][r] * inv;
  }
}

extern "C" void kernel_launch(void* const* d_in, const int* in_sizes, int n_in,
                              void* d_out, int out_size, void* d_ws, size_t ws_size,
                              hipStream_t stream) {
  const float* x = (const float*)d_in[0];
  const float* Wq = (const float*)d_in[1];
  const float* Wk = (const float*)d_in[2];
  const float* Wv = (const float*)d_in[3];
  float* out = (float*)d_out;

  char* ws = (char*)d_ws;
  const size_t QKV_BYTES = (size_t)64 * 512 * 192 * 2;  // 12,582,912
  unsigned short* q_ws = (unsigned short*)(ws);
  unsigned short* k_ws = (unsigned short*)(ws + QKV_BYTES);
  unsigned short* v_ws = (unsigned short*)(ws + 2 * QKV_BYTES);
  unsigned short* Wt = (unsigned short*)(ws + 3 * QKV_BYTES);  // 884,736 B image

  hipLaunchKernelGGL(prep_w_kernel, dim3(216), dim3(256), 0, stream, Wq, Wk, Wv, Wt);
  hipLaunchKernelGGL(proj_kernel, dim3(256, 3), dim3(256), 0, stream, x, Wt, q_ws, k_ws, v_ws);
  hipLaunchKernelGGL(attn_kernel, dim3(8, 64), dim3(256), 0, stream, q_ws, k_ws, v_ws, out);
}